// Round 1
// baseline (226.772 us; speedup 1.0000x reference)
//
#include <hip/hip_runtime.h>
#include <math.h>

// Problem constants (match reference)
constexpr int B_ = 2048;
constexpr int T_ = 50;
constexpr int N_ = 100;
constexpr int D_ = 512;
constexpr int NTOT = T_ + N_;   // 150 dots per example

// One block per example. 256 threads = 4 waves; wave w handles dots w, w+4, ...
// features[b] is hoisted into 8 registers/lane (2x float4) -- zero LDS traffic
// in the hot loop; only the gathered W-row reads hit memory.
__global__ __launch_bounds__(256, 8) void nsl_kernel(
    const float* __restrict__ features,
    const int* __restrict__ targets,
    const int* __restrict__ noises,
    const float* __restrict__ W,
    float* __restrict__ out)
{
    const int b    = blockIdx.x;
    const int tid  = threadIdx.x;
    const int lane = tid & 63;
    const int wave = tid >> 6;

    __shared__ int   s_idx[NTOT];
    __shared__ float s_wsum[4];

    // Stage the 150 gather indices (targets then noises) in LDS.
    if (tid < T_)          s_idx[tid] = targets[(size_t)b * T_ + tid];
    else if (tid < NTOT)   s_idx[tid] = noises[(size_t)b * N_ + (tid - T_)];
    __syncthreads();

    // Hoist features[b]: lane reads float4 at [lane] and [lane+64] (coalesced).
    const float4* f4 = reinterpret_cast<const float4*>(features + (size_t)b * D_);
    const float4 fa = f4[lane];
    const float4 fb = f4[lane + 64];

    float acc = 0.f;

    for (int t = wave; t < NTOT; t += 4) {
        const int idx = s_idx[t];
        const float4* w4 = reinterpret_cast<const float4*>(W + (size_t)idx * D_);
        const float4 wa = w4[lane];
        const float4 wb = w4[lane + 64];

        float p = wa.x * fa.x + wa.y * fa.y + wa.z * fa.z + wa.w * fa.w
                + wb.x * fb.x + wb.y * fb.y + wb.z * fb.z + wb.w * fb.w;

        // 64-lane butterfly reduce; all lanes end with the full dot.
        #pragma unroll
        for (int s = 32; s >= 1; s >>= 1)
            p += __shfl_xor(p, s, 64);

        // targets contribute logsigmoid(+dot), noises logsigmoid(-dot)
        const float x = (t < T_) ? p : -p;
        // stable: logsigmoid(x) = min(x,0) - log1p(exp(-|x|))
        const float ls = fminf(x, 0.f) - log1pf(__expf(-fabsf(x)));
        acc += ls;   // identical on all lanes; only lane 0 publishes
    }

    if (lane == 0) s_wsum[wave] = acc;
    __syncthreads();

    if (tid == 0) {
        const float s = s_wsum[0] + s_wsum[1] + s_wsum[2] + s_wsum[3];
        atomicAdd(out, -s / (float)NTOT);
    }
}

extern "C" void kernel_launch(void* const* d_in, const int* in_sizes, int n_in,
                              void* d_out, int out_size, void* d_ws, size_t ws_size,
                              hipStream_t stream) {
    const float* features = (const float*)d_in[0];
    const int*   targets  = (const int*)d_in[1];
    const int*   noises   = (const int*)d_in[2];
    const float* W        = (const float*)d_in[3];
    float*       out      = (float*)d_out;

    // Harness poisons d_out with 0xAA before every timed launch.
    hipMemsetAsync(out, 0, sizeof(float), stream);

    nsl_kernel<<<B_, 256, 0, stream>>>(features, targets, noises, W, out);
}

// Round 2
// 224.070 us; speedup vs baseline: 1.0121x; 1.0121x over previous
//
#include <hip/hip_runtime.h>
#include <math.h>

// Problem constants (match reference)
constexpr int B_   = 2048;
constexpr int T_   = 50;
constexpr int N_   = 100;
constexpr int D_   = 512;
constexpr int NTOT = T_ + N_;     // 150 dots per example
constexpr int NPAD = 152;         // padded to 19 chunks of 8
constexpr int NCHK = NPAD / 8;    // 19

// One block per example, 4 waves. Each wave processes 8 rows per pass:
// per-lane partials p[0..7] are reduced with a multi-row butterfly
// (xor 1,2,4 fold row bits into lane bits; xor 8,16,32 finish), so lane l
// ends with the FULL dot of row 8k+(l&7). Amortized cost per row:
// ~1.25 shuffles + ~12 VALU (vs 6 shuffles + ~34 VALU in the naive
// one-row-at-a-time reduce), and logsigmoid runs once per 8 rows per lane.
__global__ __launch_bounds__(256, 8) void nsl_kernel(
    const float* __restrict__ features,
    const int* __restrict__ targets,
    const int* __restrict__ noises,
    const float* __restrict__ W,
    float* __restrict__ out)
{
    const int b    = blockIdx.x;
    const int tid  = threadIdx.x;
    const int lane = tid & 63;
    const int wave = tid >> 6;

    __shared__ int   s_idx[NPAD];
    __shared__ float s_wsum[4];

    // Stage the gather indices (targets then noises); pad with row 0.
    if (tid < T_)          s_idx[tid] = targets[(size_t)b * T_ + tid];
    else if (tid < NTOT)   s_idx[tid] = noises[(size_t)b * N_ + (tid - T_)];
    else if (tid < NPAD)   s_idx[tid] = 0;   // padded rows masked from acc
    __syncthreads();

    // Hoist features[b] into registers: 2x float4 per lane, coalesced.
    const float4* f4 = reinterpret_cast<const float4*>(features + (size_t)b * D_);
    const float4 fa = f4[lane];
    const float4 fb = f4[lane + 64];

    float acc = 0.f;

    for (int k = wave; k < NCHK; k += 4) {
        float p[8];
        #pragma unroll
        for (int j = 0; j < 8; ++j) {
            const int idx = s_idx[8 * k + j];
            const float4* w4 = reinterpret_cast<const float4*>(W + (size_t)idx * D_);
            const float4 wa = w4[lane];
            const float4 wb = w4[lane + 64];
            p[j] = wa.x * fa.x + wa.y * fa.y + wa.z * fa.z + wa.w * fa.w
                 + wb.x * fb.x + wb.y * fb.y + wb.z * fb.z + wb.w * fb.w;
        }

        // Multi-row butterfly: fold row-bit j into lane-bit j (xor 1,2,4).
        #pragma unroll
        for (int j = 0; j < 4; ++j) {
            const float a = p[2 * j], c = p[2 * j + 1];
            const float own = (lane & 1) ? c : a;
            const float oth = (lane & 1) ? a : c;
            p[j] = own + __shfl_xor(oth, 1, 64);
        }
        #pragma unroll
        for (int j = 0; j < 2; ++j) {
            const float a = p[2 * j], c = p[2 * j + 1];
            const float own = (lane & 2) ? c : a;
            const float oth = (lane & 2) ? a : c;
            p[j] = own + __shfl_xor(oth, 2, 64);
        }
        {
            const float a = p[0], c = p[1];
            const float own = (lane & 4) ? c : a;
            const float oth = (lane & 4) ? a : c;
            p[0] = own + __shfl_xor(oth, 4, 64);
        }
        float q = p[0];
        q += __shfl_xor(q, 8, 64);
        q += __shfl_xor(q, 16, 64);
        q += __shfl_xor(q, 32, 64);
        // lane l now holds the full 512-wide dot of row 8k + (l&7)

        const int r = 8 * k + (lane & 7);
        const float x  = (r < T_) ? q : -q;       // noises use -dot
        // stable logsigmoid with fast transcendentals (threshold is 29.4)
        const float ls = fminf(x, 0.f) - __logf(1.f + __expf(-fabsf(x)));
        if (r < NTOT) acc += ls;                  // each row counted 8x/wave
    }

    // Wave-reduce acc; every row is replicated across 8 lane-groups.
    #pragma unroll
    for (int s = 32; s >= 1; s >>= 1)
        acc += __shfl_xor(acc, s, 64);

    if (lane == 0) s_wsum[wave] = acc;
    __syncthreads();

    if (tid == 0) {
        const float s = s_wsum[0] + s_wsum[1] + s_wsum[2] + s_wsum[3];
        atomicAdd(out, -s / (8.0f * (float)NTOT));
    }
}

extern "C" void kernel_launch(void* const* d_in, const int* in_sizes, int n_in,
                              void* d_out, int out_size, void* d_ws, size_t ws_size,
                              hipStream_t stream) {
    const float* features = (const float*)d_in[0];
    const int*   targets  = (const int*)d_in[1];
    const int*   noises   = (const int*)d_in[2];
    const float* W        = (const float*)d_in[3];
    float*       out      = (float*)d_out;

    // Harness poisons d_out with 0xAA before every timed launch.
    hipMemsetAsync(out, 0, sizeof(float), stream);

    nsl_kernel<<<B_, 256, 0, stream>>>(features, targets, noises, W, out);
}